// Round 1
// baseline (17477.220 us; speedup 1.0000x reference)
//
#include <hip/hip_runtime.h>
#include <math.h>

// ---------------------------------------------------------------------------
// LSTMMeasurementPredictor: B=131072, H=128, NQ=2, P=32, D_IN=17, T=16
// Fused single-kernel fp32.
//   - block = 512 threads, 64 batch elements/block (lane = element)
//   - thread (e, grp) owns 16 LSTM channels per unit; c-state in registers
//   - weights reordered on-device into ws as [k][channel][gate] so weight
//     addresses are wave-uniform -> scalar s_load; activations in LDS [k][64]
//   - LDS trimmed to <80KB (two-phase projection scratch) -> 2 blocks/CU
// ---------------------------------------------------------------------------

constexpr int T_STEPS = 16;

__device__ __forceinline__ float fast_rcp(float x) { return __builtin_amdgcn_rcpf(x); }
__device__ __forceinline__ float sigmoid_f(float x) { return fast_rcp(1.f + __expf(-x)); }
__device__ __forceinline__ float tanh_f(float x) {
  // tanh(x) = 1 - 2/(1+e^{2x});  robust at +/-inf
  return fmaf(-2.f, fast_rcp(1.f + __expf(2.f * x)), 1.f);
}

// ws layout (float offsets)
#define OFF_GENWX 0        // [17][128][4]
#define OFF_GENWH 8704     // [128][128][4]
#define OFF_L0WX  74240    // [17][128][4]
#define OFF_L0WH  82944    // [32][128][4]
#define OFF_L1WX  99328    // [32][128][4]
#define OFF_L1WH  115712   // [32][128][4]
#define OFF_GENB  132096   // [128][4]
#define OFF_L0B   132608
#define OFF_L1B   133120
// total 133632 floats = 534528 bytes

// dst[(k*128+n)*4+g] = src[(g*128+n)*K + k]   (src is torch (4H,K) row-major)
__global__ void reorder_w(const float* __restrict__ src, float* __restrict__ dst,
                          int K, int total) {
  int i = blockIdx.x * blockDim.x + threadIdx.x;
  if (i < total) {
    int g = i & 3;
    int n = (i >> 2) & 127;
    int k = i >> 9;
    dst[i] = src[(g * 128 + n) * K + k];
  }
}

// dst[n*4+g] = bih[g*128+n] + bhh[g*128+n]
__global__ void combine_bias(const float* __restrict__ a, const float* __restrict__ b,
                             float* __restrict__ dst) {
  int i = blockIdx.x * blockDim.x + threadIdx.x;
  if (i < 512) {
    int g = i & 3;
    int n = i >> 2;
    dst[i] = a[g * 128 + n] + b[g * 128 + n];
  }
}

// One LSTM gate pass for 16 channels of one element.
// shIn/shH are LDS, layout [k][64]; Wx/Wh are reordered [k][128][4]; Bc is [128][4].
template <int KX, int KH>
__device__ __forceinline__ void lstm_unit(const float* __restrict__ shIn,
                                          const float* __restrict__ Wx,
                                          const float* __restrict__ shH,
                                          const float* __restrict__ Wh,
                                          const float* __restrict__ Bc,
                                          int n0, int e,
                                          float* __restrict__ cst,
                                          float* __restrict__ uout) {
  float acc[16][4];
#pragma unroll
  for (int j = 0; j < 16; ++j) {
#pragma unroll
    for (int g = 0; g < 4; ++g) acc[j][g] = Bc[(n0 + j) * 4 + g];
  }
#pragma unroll 2
  for (int k = 0; k < KX; ++k) {
    const float s = shIn[k * 64 + e];
    const float* w = Wx + (k * 128 + n0) * 4;
#pragma unroll
    for (int j = 0; j < 16; ++j)
#pragma unroll
      for (int g = 0; g < 4; ++g) acc[j][g] = fmaf(w[j * 4 + g], s, acc[j][g]);
  }
#pragma unroll 2
  for (int k = 0; k < KH; ++k) {
    const float s = shH[k * 64 + e];
    const float* w = Wh + (k * 128 + n0) * 4;
#pragma unroll
    for (int j = 0; j < 16; ++j)
#pragma unroll
      for (int g = 0; g < 4; ++g) acc[j][g] = fmaf(w[j * 4 + g], s, acc[j][g]);
  }
#pragma unroll
  for (int j = 0; j < 16; ++j) {
    float gi = sigmoid_f(acc[j][0]);
    float gf = sigmoid_f(acc[j][1]);
    float gg = tanh_f(acc[j][2]);
    float go = sigmoid_f(acc[j][3]);
    float cn = fmaf(gf, cst[j], gi * gg);
    cst[j] = cn;
    uout[j] = go * tanh_f(cn);
  }
}

__global__ __launch_bounds__(512, 4) void lstm_fused(
    const float* __restrict__ measurement, const float* __restrict__ basis_r,
    const float* __restrict__ basis_i, const float* __restrict__ rho,
    const float* __restrict__ h0, const float* __restrict__ c0,
    const float* __restrict__ Wp, const float* __restrict__ bp,
    const float* __restrict__ Whr0, const float* __restrict__ Whr1,
    const float* __restrict__ ws, float* __restrict__ out) {
  __shared__ float sh_x[17 * 64];     // seq input, [k][64]                  4352 B
  __shared__ float sh_genH[128 * 64]; // generator hidden                   32768 B
  __shared__ float sh_l0H[32 * 64];   // layer0 projected h (= layer1 in)    8192 B
  __shared__ float sh_l1H[32 * 64];   // layer1 projected h                  8192 B
  __shared__ float sh_uh[64 * 64];    // half-sized u scratch (2-phase)     16384 B
  __shared__ float sh_v[8 * 64];      // projector output                    2048 B
  __shared__ float sh_rho[32 * 65];   // rho staged [i][e], stride 65        8320 B
  // total 80256 B <= 81920 -> 2 blocks/CU

  const int tid = threadIdx.x;
  const int e = tid & 63;
  const int grp = __builtin_amdgcn_readfirstlane(tid >> 6); // 0..7, wave-uniform
  const int n0 = grp * 16;
  const int be = blockIdx.x * 64 + e;

  const float* genWx = ws + OFF_GENWX;
  const float* genWh = ws + OFF_GENWH;
  const float* l0Wx = ws + OFF_L0WX;
  const float* l0Wh = ws + OFF_L0WH;
  const float* l1Wx = ws + OFF_L1WX;
  const float* l1Wh = ws + OFF_L1WH;
  const float* genB = ws + OFF_GENB;
  const float* l0B = ws + OFF_L0B;
  const float* l1B = ws + OFF_L1B;

  // ---- init: x0 = [measurement, stack(basis_r,basis_i,-1).reshape(16)] ----
  for (int idx = tid; idx < 17 * 64; idx += 512) {
    int k = idx >> 6, ee = idx & 63;
    int bee = blockIdx.x * 64 + ee;
    float val;
    if (k == 0) {
      val = measurement[bee];
    } else {
      int m = k - 1; // m = q*8+i*4+j*2+c
      const float* src = (m & 1) ? basis_i : basis_r;
      val = src[bee * 8 + (m >> 1)];
    }
    sh_x[idx] = val;
  }
  for (int idx = tid; idx < 128 * 64; idx += 512) {
    int k = idx >> 6, ee = idx & 63;
    sh_genH[idx] = h0[(blockIdx.x * 64 + ee) * 128 + k];
  }
  for (int idx = tid; idx < 32 * 64; idx += 512) {
    sh_l0H[idx] = 0.f;
    sh_l1H[idx] = 0.f;
  }
  // stage rho once: sh_rho[i][e] = rho[be*32 + i]  (coalesced global reads)
  for (int idx = tid; idx < 32 * 64; idx += 512) {
    int ee = idx >> 5, i = idx & 31;
    sh_rho[i * 65 + ee] = rho[(blockIdx.x * 64 + ee) * 32 + i];
  }
  float cGen[16], cL0[16], cL1[16], uloc[16];
#pragma unroll
  for (int j = 0; j < 16; ++j) {
    cGen[j] = c0[be * 128 + n0 + j];
    cL0[j] = 0.f;
    cL1[j] = 0.f;
  }
  __syncthreads();

  for (int t = 0; t < T_STEPS; ++t) {
    // ---- layer0 gates (reads sh_x, sh_l0H) ----
    lstm_unit<17, 32>(sh_x, l0Wx, sh_l0H, l0Wh, l0B, n0, e, cL0, uloc);

    // ---- layer0 projection: hp = u @ Whr0^T, two half-passes over sh_uh ----
    {
      if (grp < 4) {
#pragma unroll
        for (int j = 0; j < 16; ++j) sh_uh[(n0 + j) * 64 + e] = uloc[j];
      }
      __syncthreads(); // half0 of u visible (also: all unit reads done)
      float hp[4] = {0.f, 0.f, 0.f, 0.f};
      for (int k = 0; k < 64; ++k) {
        float uv = sh_uh[k * 64 + e];
#pragma unroll
        for (int p = 0; p < 4; ++p) hp[p] = fmaf(Whr0[(grp * 4 + p) * 128 + k], uv, hp[p]);
      }
      __syncthreads(); // all reads of half0 done
      if (grp >= 4) {
#pragma unroll
        for (int j = 0; j < 16; ++j) sh_uh[(n0 - 64 + j) * 64 + e] = uloc[j];
      }
      __syncthreads(); // half1 visible
      for (int k = 0; k < 64; ++k) {
        float uv = sh_uh[k * 64 + e];
#pragma unroll
        for (int p = 0; p < 4; ++p)
          hp[p] = fmaf(Whr0[(grp * 4 + p) * 128 + 64 + k], uv, hp[p]);
      }
#pragma unroll
      for (int p = 0; p < 4; ++p) sh_l0H[(grp * 4 + p) * 64 + e] = hp[p];
    }
    __syncthreads(); // l0H visible; half1 reads done before next sh_uh store

    // ---- layer1 gates (reads sh_l0H (=y0), sh_l1H) ----
    lstm_unit<32, 32>(sh_l0H, l1Wx, sh_l1H, l1Wh, l1B, n0, e, cL1, uloc);

    // ---- layer1 projection -> output + sh_l1H ----
    {
      if (grp < 4) {
#pragma unroll
        for (int j = 0; j < 16; ++j) sh_uh[(n0 + j) * 64 + e] = uloc[j];
      }
      __syncthreads();
      float hp[4] = {0.f, 0.f, 0.f, 0.f};
      for (int k = 0; k < 64; ++k) {
        float uv = sh_uh[k * 64 + e];
#pragma unroll
        for (int p = 0; p < 4; ++p) hp[p] = fmaf(Whr1[(grp * 4 + p) * 128 + k], uv, hp[p]);
      }
      __syncthreads();
      if (grp >= 4) {
#pragma unroll
        for (int j = 0; j < 16; ++j) sh_uh[(n0 - 64 + j) * 64 + e] = uloc[j];
      }
      __syncthreads();
      for (int k = 0; k < 64; ++k) {
        float uv = sh_uh[k * 64 + e];
#pragma unroll
        for (int p = 0; p < 4; ++p)
          hp[p] = fmaf(Whr1[(grp * 4 + p) * 128 + 64 + k], uv, hp[p]);
      }
#pragma unroll
      for (int p = 0; p < 4; ++p) sh_l1H[(grp * 4 + p) * 64 + e] = hp[p];
      float4 o4 = make_float4(hp[0], hp[1], hp[2], hp[3]);
      *(float4*)(out + be * 512 + t * 32 + grp * 4) = o4;
    }

    // ---- generator step (produces x_{t+1}), skipped on last step ----
    if (t < T_STEPS - 1) {
      lstm_unit<17, 128>(sh_x, genWx, sh_genH, genWh, genB, n0, e, cGen, uloc);
      __syncthreads(); // all reads of old sh_genH (and sh_uh half1) complete
#pragma unroll
      for (int j = 0; j < 16; ++j) sh_genH[(n0 + j) * 64 + e] = uloc[j];
      __syncthreads();

      // projector v[r=grp] = bp[r] + Wp[r,:] . genH
      {
        float acc = bp[grp];
        for (int k = 0; k < 128; ++k) acc = fmaf(Wp[grp * 128 + k], sh_genH[k * 64 + e], acc);
        sh_v[grp * 64 + e] = acc;
      }
      __syncthreads();

      // measurement: one thread per element
      if (tid < 64) {
        float v0[8];
#pragma unroll
        for (int r = 0; r < 8; ++r) v0[r] = sh_v[r * 64 + e];
        float M[2][2][2][2]; // [q][i][j][re/im]
#pragma unroll
        for (int q = 0; q < 2; ++q) {
          float b0r = v0[q * 4 + 0], b0i = v0[q * 4 + 1];
          float b1r = v0[q * 4 + 2], b1i = v0[q * 4 + 3];
          float m00 = b0r * b0r + b0i * b0i;
          float m11 = b1r * b1r + b1i * b1i;
          float m01r = b0r * b1r + b0i * b1i;
          float m01i = b0i * b1r - b0r * b1i;
          float inv = fast_rcp(m00 + m11);
          M[q][0][0][0] = m00 * inv;  M[q][0][0][1] = 0.f;
          M[q][0][1][0] = m01r * inv; M[q][0][1][1] = m01i * inv;
          M[q][1][0][0] = m01r * inv; M[q][1][0][1] = -m01i * inv;
          M[q][1][1][0] = m11 * inv;  M[q][1][1][1] = 0.f;
        }
        float meas = 0.f;
#pragma unroll
        for (int a = 0; a < 2; ++a)
#pragma unroll
          for (int cc = 0; cc < 2; ++cc) {
            float t0r = M[0][a][cc][0], t0i = M[0][a][cc][1];
#pragma unroll
            for (int bq = 0; bq < 2; ++bq)
#pragma unroll
              for (int d = 0; d < 2; ++d) {
                float t1r = M[1][bq][d][0], t1i = M[1][bq][d][1];
                float pr = t0r * t1r - t0i * t1i;
                float pi = t0r * t1i + t0i * t1r;
                int rrow = cc * 2 + d, rcol = a * 2 + bq;
                float zr = sh_rho[(rrow * 4 + rcol) * 65 + e];
                float zi = sh_rho[(16 + rrow * 4 + rcol) * 65 + e];
                meas += pr * zr - pi * zi;
              }
          }
        sh_x[0 * 64 + e] = meas;
#pragma unroll
        for (int q = 0; q < 2; ++q)
#pragma unroll
          for (int i = 0; i < 2; ++i)
#pragma unroll
            for (int j = 0; j < 2; ++j) {
              sh_x[(1 + q * 8 + i * 4 + j * 2 + 0) * 64 + e] = M[q][i][j][0];
              sh_x[(1 + q * 8 + i * 4 + j * 2 + 1) * 64 + e] = M[q][i][j][1];
            }
      }
      __syncthreads();
    }
  }
}

extern "C" void kernel_launch(void* const* d_in, const int* in_sizes, int n_in,
                              void* d_out, int out_size, void* d_ws, size_t ws_size,
                              hipStream_t stream) {
  const float* measurement = (const float*)d_in[0];
  const float* basis_r = (const float*)d_in[1];
  const float* basis_i = (const float*)d_in[2];
  const float* rho = (const float*)d_in[3];
  const float* h0 = (const float*)d_in[4];
  const float* c0 = (const float*)d_in[5];
  const float* Wih_cell = (const float*)d_in[6];
  const float* Whh_cell = (const float*)d_in[7];
  const float* bih_cell = (const float*)d_in[8];
  const float* bhh_cell = (const float*)d_in[9];
  const float* Wp = (const float*)d_in[10];
  const float* bp = (const float*)d_in[11];
  const float* Wih0 = (const float*)d_in[12];
  const float* Whh0 = (const float*)d_in[13];
  const float* bih0 = (const float*)d_in[14];
  const float* bhh0 = (const float*)d_in[15];
  const float* Whr0 = (const float*)d_in[16];
  const float* Wih1 = (const float*)d_in[17];
  const float* Whh1 = (const float*)d_in[18];
  const float* bih1 = (const float*)d_in[19];
  const float* bhh1 = (const float*)d_in[20];
  const float* Whr1 = (const float*)d_in[21];
  float* out = (float*)d_out;
  float* ws = (float*)d_ws;

  const int B = in_sizes[0];

  // re-pack weights every call (ws is re-poisoned before each timed launch)
  reorder_w<<<(512 * 17 + 255) / 256, 256, 0, stream>>>(Wih_cell, ws + OFF_GENWX, 17, 512 * 17);
  reorder_w<<<(512 * 128 + 255) / 256, 256, 0, stream>>>(Whh_cell, ws + OFF_GENWH, 128, 512 * 128);
  reorder_w<<<(512 * 17 + 255) / 256, 256, 0, stream>>>(Wih0, ws + OFF_L0WX, 17, 512 * 17);
  reorder_w<<<(512 * 32 + 255) / 256, 256, 0, stream>>>(Whh0, ws + OFF_L0WH, 32, 512 * 32);
  reorder_w<<<(512 * 32 + 255) / 256, 256, 0, stream>>>(Wih1, ws + OFF_L1WX, 32, 512 * 32);
  reorder_w<<<(512 * 32 + 255) / 256, 256, 0, stream>>>(Whh1, ws + OFF_L1WH, 32, 512 * 32);
  combine_bias<<<2, 256, 0, stream>>>(bih_cell, bhh_cell, ws + OFF_GENB);
  combine_bias<<<2, 256, 0, stream>>>(bih0, bhh0, ws + OFF_L0B);
  combine_bias<<<2, 256, 0, stream>>>(bih1, bhh1, ws + OFF_L1B);

  lstm_fused<<<B / 64, 512, 0, stream>>>(measurement, basis_r, basis_i, rho, h0, c0,
                                         Wp, bp, Whr0, Whr1, ws, out);
}

// Round 2
// 16773.344 us; speedup vs baseline: 1.0420x; 1.0420x over previous
//
#include <hip/hip_runtime.h>
#include <math.h>

// ---------------------------------------------------------------------------
// LSTMMeasurementPredictor: B=131072, H=128, NQ=2, P=32, D_IN=17, T=16
// Fused single-kernel fp32.
//   - block = 512 threads, 64 batch elements/block (lane = element)
//   - thread (e, grp) owns 16 LSTM channels per unit; c-state in registers
//   - weights reordered on-device into ws as [k][channel][gate] so weight
//     addresses are wave-uniform -> scalar s_load; activations in LDS [k][64]
//   - LDS 80256B (<80KB) -> 2 blocks/CU
//   - __launch_bounds__(512, 2): 2nd arg is min BLOCKS/CU (CUDA semantics) ->
//     VGPR cap 128. (512,4) forced a 64-VGPR cap and 6.7GB of scratch spills.
// ---------------------------------------------------------------------------

constexpr int T_STEPS = 16;

__device__ __forceinline__ float fast_rcp(float x) { return __builtin_amdgcn_rcpf(x); }
__device__ __forceinline__ float sigmoid_f(float x) { return fast_rcp(1.f + __expf(-x)); }
__device__ __forceinline__ float tanh_f(float x) {
  // tanh(x) = 1 - 2/(1+e^{2x});  robust at +/-inf
  return fmaf(-2.f, fast_rcp(1.f + __expf(2.f * x)), 1.f);
}

// ws layout (float offsets)
#define OFF_GENWX 0        // [17][128][4]
#define OFF_GENWH 8704     // [128][128][4]
#define OFF_L0WX  74240    // [17][128][4]
#define OFF_L0WH  82944    // [32][128][4]
#define OFF_L1WX  99328    // [32][128][4]
#define OFF_L1WH  115712   // [32][128][4]
#define OFF_GENB  132096   // [128][4]
#define OFF_L0B   132608
#define OFF_L1B   133120
// total 133632 floats = 534528 bytes

// dst[(k*128+n)*4+g] = src[(g*128+n)*K + k]   (src is torch (4H,K) row-major)
__global__ void reorder_w(const float* __restrict__ src, float* __restrict__ dst,
                          int K, int total) {
  int i = blockIdx.x * blockDim.x + threadIdx.x;
  if (i < total) {
    int g = i & 3;
    int n = (i >> 2) & 127;
    int k = i >> 9;
    dst[i] = src[(g * 128 + n) * K + k];
  }
}

// dst[n*4+g] = bih[g*128+n] + bhh[g*128+n]
__global__ void combine_bias(const float* __restrict__ a, const float* __restrict__ b,
                             float* __restrict__ dst) {
  int i = blockIdx.x * blockDim.x + threadIdx.x;
  if (i < 512) {
    int g = i & 3;
    int n = i >> 2;
    dst[i] = a[g * 128 + n] + b[g * 128 + n];
  }
}

// One LSTM gate pass for 16 channels of one element.
// shIn/shH are LDS, layout [k][64]; Wx/Wh are reordered [k][128][4]; Bc is [128][4].
template <int KX, int KH>
__device__ __forceinline__ void lstm_unit(const float* __restrict__ shIn,
                                          const float* __restrict__ Wx,
                                          const float* __restrict__ shH,
                                          const float* __restrict__ Wh,
                                          const float* __restrict__ Bc,
                                          int n0, int e,
                                          float* __restrict__ cst,
                                          float* __restrict__ uout) {
  float acc[16][4];
#pragma unroll
  for (int j = 0; j < 16; ++j) {
#pragma unroll
    for (int g = 0; g < 4; ++g) acc[j][g] = Bc[(n0 + j) * 4 + g];
  }
#pragma unroll 2
  for (int k = 0; k < KX; ++k) {
    const float s = shIn[k * 64 + e];
    const float* w = Wx + (k * 128 + n0) * 4;
#pragma unroll
    for (int j = 0; j < 16; ++j)
#pragma unroll
      for (int g = 0; g < 4; ++g) acc[j][g] = fmaf(w[j * 4 + g], s, acc[j][g]);
  }
#pragma unroll 2
  for (int k = 0; k < KH; ++k) {
    const float s = shH[k * 64 + e];
    const float* w = Wh + (k * 128 + n0) * 4;
#pragma unroll
    for (int j = 0; j < 16; ++j)
#pragma unroll
      for (int g = 0; g < 4; ++g) acc[j][g] = fmaf(w[j * 4 + g], s, acc[j][g]);
  }
#pragma unroll
  for (int j = 0; j < 16; ++j) {
    float gi = sigmoid_f(acc[j][0]);
    float gf = sigmoid_f(acc[j][1]);
    float gg = tanh_f(acc[j][2]);
    float go = sigmoid_f(acc[j][3]);
    float cn = fmaf(gf, cst[j], gi * gg);
    cst[j] = cn;
    uout[j] = go * tanh_f(cn);
  }
}

__global__ __launch_bounds__(512, 2) void lstm_fused(
    const float* __restrict__ measurement, const float* __restrict__ basis_r,
    const float* __restrict__ basis_i, const float* __restrict__ rho,
    const float* __restrict__ h0, const float* __restrict__ c0,
    const float* __restrict__ Wp, const float* __restrict__ bp,
    const float* __restrict__ Whr0, const float* __restrict__ Whr1,
    const float* __restrict__ ws, float* __restrict__ out) {
  __shared__ float sh_x[17 * 64];     // seq input, [k][64]                  4352 B
  __shared__ float sh_genH[128 * 64]; // generator hidden                   32768 B
  __shared__ float sh_l0H[32 * 64];   // layer0 projected h (= layer1 in)    8192 B
  __shared__ float sh_l1H[32 * 64];   // layer1 projected h                  8192 B
  __shared__ float sh_uh[64 * 64];    // half-sized u scratch (2-phase)     16384 B
  __shared__ float sh_v[8 * 64];      // projector output                    2048 B
  __shared__ float sh_rho[32 * 65];   // rho staged [i][e], stride 65        8320 B
  // total 80256 B <= 81920 -> 2 blocks/CU

  const int tid = threadIdx.x;
  const int e = tid & 63;
  const int grp = __builtin_amdgcn_readfirstlane(tid >> 6); // 0..7, wave-uniform
  const int n0 = grp * 16;
  const int be = blockIdx.x * 64 + e;

  const float* genWx = ws + OFF_GENWX;
  const float* genWh = ws + OFF_GENWH;
  const float* l0Wx = ws + OFF_L0WX;
  const float* l0Wh = ws + OFF_L0WH;
  const float* l1Wx = ws + OFF_L1WX;
  const float* l1Wh = ws + OFF_L1WH;
  const float* genB = ws + OFF_GENB;
  const float* l0B = ws + OFF_L0B;
  const float* l1B = ws + OFF_L1B;

  // ---- init: x0 = [measurement, stack(basis_r,basis_i,-1).reshape(16)] ----
  for (int idx = tid; idx < 17 * 64; idx += 512) {
    int k = idx >> 6, ee = idx & 63;
    int bee = blockIdx.x * 64 + ee;
    float val;
    if (k == 0) {
      val = measurement[bee];
    } else {
      int m = k - 1; // m = q*8+i*4+j*2+c
      const float* src = (m & 1) ? basis_i : basis_r;
      val = src[bee * 8 + (m >> 1)];
    }
    sh_x[idx] = val;
  }
  for (int idx = tid; idx < 128 * 64; idx += 512) {
    int k = idx >> 6, ee = idx & 63;
    sh_genH[idx] = h0[(blockIdx.x * 64 + ee) * 128 + k];
  }
  for (int idx = tid; idx < 32 * 64; idx += 512) {
    sh_l0H[idx] = 0.f;
    sh_l1H[idx] = 0.f;
  }
  // stage rho once: sh_rho[i][e] = rho[be*32 + i]  (coalesced global reads)
  for (int idx = tid; idx < 32 * 64; idx += 512) {
    int ee = idx >> 5, i = idx & 31;
    sh_rho[i * 65 + ee] = rho[(blockIdx.x * 64 + ee) * 32 + i];
  }
  float cGen[16], cL0[16], cL1[16], uloc[16];
#pragma unroll
  for (int j = 0; j < 16; ++j) {
    cGen[j] = c0[be * 128 + n0 + j];
    cL0[j] = 0.f;
    cL1[j] = 0.f;
  }
  __syncthreads();

  for (int t = 0; t < T_STEPS; ++t) {
    // ---- layer0 gates (reads sh_x, sh_l0H) ----
    lstm_unit<17, 32>(sh_x, l0Wx, sh_l0H, l0Wh, l0B, n0, e, cL0, uloc);

    // ---- layer0 projection: hp = u @ Whr0^T, two half-passes over sh_uh ----
    {
      if (grp < 4) {
#pragma unroll
        for (int j = 0; j < 16; ++j) sh_uh[(n0 + j) * 64 + e] = uloc[j];
      }
      __syncthreads(); // half0 of u visible (also: all unit reads done)
      float hp[4] = {0.f, 0.f, 0.f, 0.f};
      for (int k = 0; k < 64; ++k) {
        float uv = sh_uh[k * 64 + e];
#pragma unroll
        for (int p = 0; p < 4; ++p) hp[p] = fmaf(Whr0[(grp * 4 + p) * 128 + k], uv, hp[p]);
      }
      __syncthreads(); // all reads of half0 done
      if (grp >= 4) {
#pragma unroll
        for (int j = 0; j < 16; ++j) sh_uh[(n0 - 64 + j) * 64 + e] = uloc[j];
      }
      __syncthreads(); // half1 visible
      for (int k = 0; k < 64; ++k) {
        float uv = sh_uh[k * 64 + e];
#pragma unroll
        for (int p = 0; p < 4; ++p)
          hp[p] = fmaf(Whr0[(grp * 4 + p) * 128 + 64 + k], uv, hp[p]);
      }
#pragma unroll
      for (int p = 0; p < 4; ++p) sh_l0H[(grp * 4 + p) * 64 + e] = hp[p];
    }
    __syncthreads(); // l0H visible; half1 reads done before next sh_uh store

    // ---- layer1 gates (reads sh_l0H (=y0), sh_l1H) ----
    lstm_unit<32, 32>(sh_l0H, l1Wx, sh_l1H, l1Wh, l1B, n0, e, cL1, uloc);

    // ---- layer1 projection -> output + sh_l1H ----
    {
      if (grp < 4) {
#pragma unroll
        for (int j = 0; j < 16; ++j) sh_uh[(n0 + j) * 64 + e] = uloc[j];
      }
      __syncthreads();
      float hp[4] = {0.f, 0.f, 0.f, 0.f};
      for (int k = 0; k < 64; ++k) {
        float uv = sh_uh[k * 64 + e];
#pragma unroll
        for (int p = 0; p < 4; ++p) hp[p] = fmaf(Whr1[(grp * 4 + p) * 128 + k], uv, hp[p]);
      }
      __syncthreads();
      if (grp >= 4) {
#pragma unroll
        for (int j = 0; j < 16; ++j) sh_uh[(n0 - 64 + j) * 64 + e] = uloc[j];
      }
      __syncthreads();
      for (int k = 0; k < 64; ++k) {
        float uv = sh_uh[k * 64 + e];
#pragma unroll
        for (int p = 0; p < 4; ++p)
          hp[p] = fmaf(Whr1[(grp * 4 + p) * 128 + 64 + k], uv, hp[p]);
      }
#pragma unroll
      for (int p = 0; p < 4; ++p) sh_l1H[(grp * 4 + p) * 64 + e] = hp[p];
      float4 o4 = make_float4(hp[0], hp[1], hp[2], hp[3]);
      *(float4*)(out + be * 512 + t * 32 + grp * 4) = o4;
    }

    // ---- generator step (produces x_{t+1}), skipped on last step ----
    if (t < T_STEPS - 1) {
      lstm_unit<17, 128>(sh_x, genWx, sh_genH, genWh, genB, n0, e, cGen, uloc);
      __syncthreads(); // all reads of old sh_genH (and sh_uh half1) complete
#pragma unroll
      for (int j = 0; j < 16; ++j) sh_genH[(n0 + j) * 64 + e] = uloc[j];
      __syncthreads();

      // projector v[r=grp] = bp[r] + Wp[r,:] . genH
      {
        float acc = bp[grp];
        for (int k = 0; k < 128; ++k) acc = fmaf(Wp[grp * 128 + k], sh_genH[k * 64 + e], acc);
        sh_v[grp * 64 + e] = acc;
      }
      __syncthreads();

      // measurement: one thread per element
      if (tid < 64) {
        float v0[8];
#pragma unroll
        for (int r = 0; r < 8; ++r) v0[r] = sh_v[r * 64 + e];
        float M[2][2][2][2]; // [q][i][j][re/im]
#pragma unroll
        for (int q = 0; q < 2; ++q) {
          float b0r = v0[q * 4 + 0], b0i = v0[q * 4 + 1];
          float b1r = v0[q * 4 + 2], b1i = v0[q * 4 + 3];
          float m00 = b0r * b0r + b0i * b0i;
          float m11 = b1r * b1r + b1i * b1i;
          float m01r = b0r * b1r + b0i * b1i;
          float m01i = b0i * b1r - b0r * b1i;
          float inv = fast_rcp(m00 + m11);
          M[q][0][0][0] = m00 * inv;  M[q][0][0][1] = 0.f;
          M[q][0][1][0] = m01r * inv; M[q][0][1][1] = m01i * inv;
          M[q][1][0][0] = m01r * inv; M[q][1][0][1] = -m01i * inv;
          M[q][1][1][0] = m11 * inv;  M[q][1][1][1] = 0.f;
        }
        float meas = 0.f;
#pragma unroll
        for (int a = 0; a < 2; ++a)
#pragma unroll
          for (int cc = 0; cc < 2; ++cc) {
            float t0r = M[0][a][cc][0], t0i = M[0][a][cc][1];
#pragma unroll
            for (int bq = 0; bq < 2; ++bq)
#pragma unroll
              for (int d = 0; d < 2; ++d) {
                float t1r = M[1][bq][d][0], t1i = M[1][bq][d][1];
                float pr = t0r * t1r - t0i * t1i;
                float pi = t0r * t1i + t0i * t1r;
                int rrow = cc * 2 + d, rcol = a * 2 + bq;
                float zr = sh_rho[(rrow * 4 + rcol) * 65 + e];
                float zi = sh_rho[(16 + rrow * 4 + rcol) * 65 + e];
                meas += pr * zr - pi * zi;
              }
          }
        sh_x[0 * 64 + e] = meas;
#pragma unroll
        for (int q = 0; q < 2; ++q)
#pragma unroll
          for (int i = 0; i < 2; ++i)
#pragma unroll
            for (int j = 0; j < 2; ++j) {
              sh_x[(1 + q * 8 + i * 4 + j * 2 + 0) * 64 + e] = M[q][i][j][0];
              sh_x[(1 + q * 8 + i * 4 + j * 2 + 1) * 64 + e] = M[q][i][j][1];
            }
      }
      __syncthreads();
    }
  }
}

extern "C" void kernel_launch(void* const* d_in, const int* in_sizes, int n_in,
                              void* d_out, int out_size, void* d_ws, size_t ws_size,
                              hipStream_t stream) {
  const float* measurement = (const float*)d_in[0];
  const float* basis_r = (const float*)d_in[1];
  const float* basis_i = (const float*)d_in[2];
  const float* rho = (const float*)d_in[3];
  const float* h0 = (const float*)d_in[4];
  const float* c0 = (const float*)d_in[5];
  const float* Wih_cell = (const float*)d_in[6];
  const float* Whh_cell = (const float*)d_in[7];
  const float* bih_cell = (const float*)d_in[8];
  const float* bhh_cell = (const float*)d_in[9];
  const float* Wp = (const float*)d_in[10];
  const float* bp = (const float*)d_in[11];
  const float* Wih0 = (const float*)d_in[12];
  const float* Whh0 = (const float*)d_in[13];
  const float* bih0 = (const float*)d_in[14];
  const float* bhh0 = (const float*)d_in[15];
  const float* Whr0 = (const float*)d_in[16];
  const float* Wih1 = (const float*)d_in[17];
  const float* Whh1 = (const float*)d_in[18];
  const float* bih1 = (const float*)d_in[19];
  const float* bhh1 = (const float*)d_in[20];
  const float* Whr1 = (const float*)d_in[21];
  float* out = (float*)d_out;
  float* ws = (float*)d_ws;

  const int B = in_sizes[0];

  // re-pack weights every call (ws is re-poisoned before each timed launch)
  reorder_w<<<(512 * 17 + 255) / 256, 256, 0, stream>>>(Wih_cell, ws + OFF_GENWX, 17, 512 * 17);
  reorder_w<<<(512 * 128 + 255) / 256, 256, 0, stream>>>(Whh_cell, ws + OFF_GENWH, 128, 512 * 128);
  reorder_w<<<(512 * 17 + 255) / 256, 256, 0, stream>>>(Wih0, ws + OFF_L0WX, 17, 512 * 17);
  reorder_w<<<(512 * 32 + 255) / 256, 256, 0, stream>>>(Whh0, ws + OFF_L0WH, 32, 512 * 32);
  reorder_w<<<(512 * 32 + 255) / 256, 256, 0, stream>>>(Wih1, ws + OFF_L1WX, 32, 512 * 32);
  reorder_w<<<(512 * 32 + 255) / 256, 256, 0, stream>>>(Whh1, ws + OFF_L1WH, 32, 512 * 32);
  combine_bias<<<2, 256, 0, stream>>>(bih_cell, bhh_cell, ws + OFF_GENB);
  combine_bias<<<2, 256, 0, stream>>>(bih0, bhh0, ws + OFF_L0B);
  combine_bias<<<2, 256, 0, stream>>>(bih1, bhh1, ws + OFF_L1B);

  lstm_fused<<<B / 64, 512, 0, stream>>>(measurement, basis_r, basis_i, rho, h0, c0,
                                         Wp, bp, Whr0, Whr1, ws, out);
}

// Round 3
// 9687.571 us; speedup vs baseline: 1.8041x; 1.7314x over previous
//
#include <hip/hip_runtime.h>
#include <math.h>

// ---------------------------------------------------------------------------
// LSTMMeasurementPredictor: B=131072, H=128, NQ=2, P=32, D_IN=17, T=16
// Fused single-kernel fp32.
//   - block = 1024 threads (16 waves), 64 batch elements/block (lane = elem)
//   - thread (e, grp) owns 8 LSTM channels per unit; c-state in registers
//   - 16 waves in ONE workgroup -> 4 waves/SIMD resident by construction
//     (multi-workgroup co-residency at 80KB LDS + >64 VGPR was never granted
//      by the scheduler in rounds 0-2; single big block sidesteps it)
//   - weights reordered into ws as [k][channel][gate] -> wave-uniform s_load
// ---------------------------------------------------------------------------

constexpr int T_STEPS = 16;

__device__ __forceinline__ float fast_rcp(float x) { return __builtin_amdgcn_rcpf(x); }
__device__ __forceinline__ float sigmoid_f(float x) { return fast_rcp(1.f + __expf(-x)); }
__device__ __forceinline__ float tanh_f(float x) {
  // tanh(x) = 1 - 2/(1+e^{2x});  robust at +/-inf
  return fmaf(-2.f, fast_rcp(1.f + __expf(2.f * x)), 1.f);
}

// ws layout (float offsets)
#define OFF_GENWX 0        // [17][128][4]
#define OFF_GENWH 8704     // [128][128][4]
#define OFF_L0WX  74240    // [17][128][4]
#define OFF_L0WH  82944    // [32][128][4]
#define OFF_L1WX  99328    // [32][128][4]
#define OFF_L1WH  115712   // [32][128][4]
#define OFF_GENB  132096   // [128][4]
#define OFF_L0B   132608
#define OFF_L1B   133120
// total 133632 floats = 534528 bytes

// dst[(k*128+n)*4+g] = src[(g*128+n)*K + k]   (src is torch (4H,K) row-major)
__global__ void reorder_w(const float* __restrict__ src, float* __restrict__ dst,
                          int K, int total) {
  int i = blockIdx.x * blockDim.x + threadIdx.x;
  if (i < total) {
    int g = i & 3;
    int n = (i >> 2) & 127;
    int k = i >> 9;
    dst[i] = src[(g * 128 + n) * K + k];
  }
}

// dst[n*4+g] = bih[g*128+n] + bhh[g*128+n]
__global__ void combine_bias(const float* __restrict__ a, const float* __restrict__ b,
                             float* __restrict__ dst) {
  int i = blockIdx.x * blockDim.x + threadIdx.x;
  if (i < 512) {
    int g = i & 3;
    int n = i >> 2;
    dst[i] = a[g * 128 + n] + b[g * 128 + n];
  }
}

// One LSTM gate pass for 8 channels of one element.
// shIn/shH are LDS, layout [k][64]; Wx/Wh are reordered [k][128][4]; Bc is [128][4].
template <int KX, int KH>
__device__ __forceinline__ void lstm_unit8(const float* __restrict__ shIn,
                                           const float* __restrict__ Wx,
                                           const float* __restrict__ shH,
                                           const float* __restrict__ Wh,
                                           const float* __restrict__ Bc,
                                           int n0, int e,
                                           float* __restrict__ cst,
                                           float* __restrict__ uout) {
  float acc[8][4];
#pragma unroll
  for (int j = 0; j < 8; ++j) {
#pragma unroll
    for (int g = 0; g < 4; ++g) acc[j][g] = Bc[(n0 + j) * 4 + g];
  }
#pragma unroll 2
  for (int k = 0; k < KX; ++k) {
    const float s = shIn[k * 64 + e];
    const float* w = Wx + (k * 128 + n0) * 4;
#pragma unroll
    for (int j = 0; j < 8; ++j)
#pragma unroll
      for (int g = 0; g < 4; ++g) acc[j][g] = fmaf(w[j * 4 + g], s, acc[j][g]);
  }
#pragma unroll 2
  for (int k = 0; k < KH; ++k) {
    const float s = shH[k * 64 + e];
    const float* w = Wh + (k * 128 + n0) * 4;
#pragma unroll
    for (int j = 0; j < 8; ++j)
#pragma unroll
      for (int g = 0; g < 4; ++g) acc[j][g] = fmaf(w[j * 4 + g], s, acc[j][g]);
  }
#pragma unroll
  for (int j = 0; j < 8; ++j) {
    float gi = sigmoid_f(acc[j][0]);
    float gf = sigmoid_f(acc[j][1]);
    float gg = tanh_f(acc[j][2]);
    float go = sigmoid_f(acc[j][3]);
    float cn = fmaf(gf, cst[j], gi * gg);
    cst[j] = cn;
    uout[j] = go * tanh_f(cn);
  }
}

__global__ __launch_bounds__(1024, 1) void lstm_fused(
    const float* __restrict__ measurement, const float* __restrict__ basis_r,
    const float* __restrict__ basis_i, const float* __restrict__ rho,
    const float* __restrict__ h0, const float* __restrict__ c0,
    const float* __restrict__ Wp, const float* __restrict__ bp,
    const float* __restrict__ Whr0, const float* __restrict__ Whr1,
    const float* __restrict__ ws, float* __restrict__ out) {
  __shared__ float sh_x[17 * 64];     // seq input, [k][64]                  4352 B
  __shared__ float sh_genH[128 * 64]; // generator hidden                   32768 B
  __shared__ float sh_l0H[32 * 64];   // layer0 projected h (= layer1 in)    8192 B
  __shared__ float sh_l1H[32 * 64];   // layer1 projected h                  8192 B
  __shared__ float sh_u[128 * 64];    // sigma(o)*tanh(c) scratch           32768 B
  __shared__ float sh_vp[16 * 64];    // projector split-k partials          4096 B
  __shared__ float sh_rho[32 * 65];   // rho staged [i][e], stride 65        8320 B
  // total 98688 B (single block per CU; 16 waves resident)

  const int tid = threadIdx.x;
  const int e = tid & 63;
  const int grp = __builtin_amdgcn_readfirstlane(tid >> 6); // 0..15, wave-uniform
  const int n0 = grp * 8;
  const int be = blockIdx.x * 64 + e;

  const float* genWx = ws + OFF_GENWX;
  const float* genWh = ws + OFF_GENWH;
  const float* l0Wx = ws + OFF_L0WX;
  const float* l0Wh = ws + OFF_L0WH;
  const float* l1Wx = ws + OFF_L1WX;
  const float* l1Wh = ws + OFF_L1WH;
  const float* genB = ws + OFF_GENB;
  const float* l0B = ws + OFF_L0B;
  const float* l1B = ws + OFF_L1B;

  // ---- init: x0 = [measurement, stack(basis_r,basis_i,-1).reshape(16)] ----
  for (int idx = tid; idx < 17 * 64; idx += 1024) {
    int k = idx >> 6, ee = idx & 63;
    int bee = blockIdx.x * 64 + ee;
    float val;
    if (k == 0) {
      val = measurement[bee];
    } else {
      int m = k - 1; // m = q*8+i*4+j*2+c
      const float* src = (m & 1) ? basis_i : basis_r;
      val = src[bee * 8 + (m >> 1)];
    }
    sh_x[idx] = val;
  }
  for (int idx = tid; idx < 128 * 64; idx += 1024) {
    int k = idx >> 6, ee = idx & 63;
    sh_genH[idx] = h0[(blockIdx.x * 64 + ee) * 128 + k];
  }
  for (int idx = tid; idx < 32 * 64; idx += 1024) {
    sh_l0H[idx] = 0.f;
    sh_l1H[idx] = 0.f;
  }
  // stage rho once: sh_rho[i][e] = rho[be*32 + i]  (coalesced global reads)
  for (int idx = tid; idx < 32 * 64; idx += 1024) {
    int ee = idx >> 5, i = idx & 31;
    sh_rho[i * 65 + ee] = rho[(blockIdx.x * 64 + ee) * 32 + i];
  }
  float cGen[8], cL0[8], cL1[8], uloc[8];
#pragma unroll
  for (int j = 0; j < 8; ++j) {
    cGen[j] = c0[be * 128 + n0 + j];
    cL0[j] = 0.f;
    cL1[j] = 0.f;
  }
  __syncthreads();

  for (int t = 0; t < T_STEPS; ++t) {
    // ---- layer0 gates (reads sh_x, sh_l0H) ----
    lstm_unit8<17, 32>(sh_x, l0Wx, sh_l0H, l0Wh, l0B, n0, e, cL0, uloc);
#pragma unroll
    for (int j = 0; j < 8; ++j) sh_u[(n0 + j) * 64 + e] = uloc[j];
    __syncthreads(); // u visible; also all reads of sh_x/sh_l0H done

    // ---- layer0 projection: rows grp*2, grp*2+1 of hp = u @ Whr0^T ----
    {
      float hp[2] = {0.f, 0.f};
      for (int k = 0; k < 128; ++k) {
        float uv = sh_u[k * 64 + e];
#pragma unroll
        for (int p = 0; p < 2; ++p) hp[p] = fmaf(Whr0[(grp * 2 + p) * 128 + k], uv, hp[p]);
      }
#pragma unroll
      for (int p = 0; p < 2; ++p) sh_l0H[(grp * 2 + p) * 64 + e] = hp[p];
    }
    __syncthreads(); // l0H visible; all sh_u reads done

    // ---- layer1 gates (reads sh_l0H (=y0), sh_l1H) ----
    lstm_unit8<32, 32>(sh_l0H, l1Wx, sh_l1H, l1Wh, l1B, n0, e, cL1, uloc);
#pragma unroll
    for (int j = 0; j < 8; ++j) sh_u[(n0 + j) * 64 + e] = uloc[j];
    __syncthreads();

    // ---- layer1 projection -> output + sh_l1H ----
    {
      float hp[2] = {0.f, 0.f};
      for (int k = 0; k < 128; ++k) {
        float uv = sh_u[k * 64 + e];
#pragma unroll
        for (int p = 0; p < 2; ++p) hp[p] = fmaf(Whr1[(grp * 2 + p) * 128 + k], uv, hp[p]);
      }
#pragma unroll
      for (int p = 0; p < 2; ++p) sh_l1H[(grp * 2 + p) * 64 + e] = hp[p];
      *(float2*)(out + be * 512 + t * 32 + grp * 2) = make_float2(hp[0], hp[1]);
    }
    __syncthreads(); // l1H visible; sh_u reads done

    // ---- generator step (produces x_{t+1}), skipped on last step ----
    if (t < T_STEPS - 1) {
      lstm_unit8<17, 128>(sh_x, genWx, sh_genH, genWh, genB, n0, e, cGen, uloc);
      __syncthreads(); // all reads of old sh_genH complete
#pragma unroll
      for (int j = 0; j < 8; ++j) sh_genH[(n0 + j) * 64 + e] = uloc[j];
      __syncthreads();

      // projector: 16 groups compute 8 rows x 2 half-k partials
      {
        int r = grp & 7, half = grp >> 3;
        float acc = half ? 0.f : bp[r];
        int kb = half * 64;
        for (int k = 0; k < 64; ++k)
          acc = fmaf(Wp[r * 128 + kb + k], sh_genH[(kb + k) * 64 + e], acc);
        sh_vp[grp * 64 + e] = acc;
      }
      __syncthreads();

      // measurement: one thread per element
      if (tid < 64) {
        float v0[8];
#pragma unroll
        for (int r = 0; r < 8; ++r) v0[r] = sh_vp[r * 64 + e] + sh_vp[(r + 8) * 64 + e];
        float M[2][2][2][2]; // [q][i][j][re/im]
#pragma unroll
        for (int q = 0; q < 2; ++q) {
          float b0r = v0[q * 4 + 0], b0i = v0[q * 4 + 1];
          float b1r = v0[q * 4 + 2], b1i = v0[q * 4 + 3];
          float m00 = b0r * b0r + b0i * b0i;
          float m11 = b1r * b1r + b1i * b1i;
          float m01r = b0r * b1r + b0i * b1i;
          float m01i = b0i * b1r - b0r * b1i;
          float inv = fast_rcp(m00 + m11);
          M[q][0][0][0] = m00 * inv;  M[q][0][0][1] = 0.f;
          M[q][0][1][0] = m01r * inv; M[q][0][1][1] = m01i * inv;
          M[q][1][0][0] = m01r * inv; M[q][1][0][1] = -m01i * inv;
          M[q][1][1][0] = m11 * inv;  M[q][1][1][1] = 0.f;
        }
        float meas = 0.f;
#pragma unroll
        for (int a = 0; a < 2; ++a)
#pragma unroll
          for (int cc = 0; cc < 2; ++cc) {
            float t0r = M[0][a][cc][0], t0i = M[0][a][cc][1];
#pragma unroll
            for (int bq = 0; bq < 2; ++bq)
#pragma unroll
              for (int d = 0; d < 2; ++d) {
                float t1r = M[1][bq][d][0], t1i = M[1][bq][d][1];
                float pr = t0r * t1r - t0i * t1i;
                float pi = t0r * t1i + t0i * t1r;
                int rrow = cc * 2 + d, rcol = a * 2 + bq;
                float zr = sh_rho[(rrow * 4 + rcol) * 65 + e];
                float zi = sh_rho[(16 + rrow * 4 + rcol) * 65 + e];
                meas += pr * zr - pi * zi;
              }
          }
        sh_x[0 * 64 + e] = meas;
#pragma unroll
        for (int q = 0; q < 2; ++q)
#pragma unroll
          for (int i = 0; i < 2; ++i)
#pragma unroll
            for (int j = 0; j < 2; ++j) {
              sh_x[(1 + q * 8 + i * 4 + j * 2 + 0) * 64 + e] = M[q][i][j][0];
              sh_x[(1 + q * 8 + i * 4 + j * 2 + 1) * 64 + e] = M[q][i][j][1];
            }
      }
      __syncthreads();
    }
  }
}

extern "C" void kernel_launch(void* const* d_in, const int* in_sizes, int n_in,
                              void* d_out, int out_size, void* d_ws, size_t ws_size,
                              hipStream_t stream) {
  const float* measurement = (const float*)d_in[0];
  const float* basis_r = (const float*)d_in[1];
  const float* basis_i = (const float*)d_in[2];
  const float* rho = (const float*)d_in[3];
  const float* h0 = (const float*)d_in[4];
  const float* c0 = (const float*)d_in[5];
  const float* Wih_cell = (const float*)d_in[6];
  const float* Whh_cell = (const float*)d_in[7];
  const float* bih_cell = (const float*)d_in[8];
  const float* bhh_cell = (const float*)d_in[9];
  const float* Wp = (const float*)d_in[10];
  const float* bp = (const float*)d_in[11];
  const float* Wih0 = (const float*)d_in[12];
  const float* Whh0 = (const float*)d_in[13];
  const float* bih0 = (const float*)d_in[14];
  const float* bhh0 = (const float*)d_in[15];
  const float* Whr0 = (const float*)d_in[16];
  const float* Wih1 = (const float*)d_in[17];
  const float* Whh1 = (const float*)d_in[18];
  const float* bih1 = (const float*)d_in[19];
  const float* bhh1 = (const float*)d_in[20];
  const float* Whr1 = (const float*)d_in[21];
  float* out = (float*)d_out;
  float* ws = (float*)d_ws;

  const int B = in_sizes[0];

  // re-pack weights every call (ws is re-poisoned before each timed launch)
  reorder_w<<<(512 * 17 + 255) / 256, 256, 0, stream>>>(Wih_cell, ws + OFF_GENWX, 17, 512 * 17);
  reorder_w<<<(512 * 128 + 255) / 256, 256, 0, stream>>>(Whh_cell, ws + OFF_GENWH, 128, 512 * 128);
  reorder_w<<<(512 * 17 + 255) / 256, 256, 0, stream>>>(Wih0, ws + OFF_L0WX, 17, 512 * 17);
  reorder_w<<<(512 * 32 + 255) / 256, 256, 0, stream>>>(Whh0, ws + OFF_L0WH, 32, 512 * 32);
  reorder_w<<<(512 * 32 + 255) / 256, 256, 0, stream>>>(Wih1, ws + OFF_L1WX, 32, 512 * 32);
  reorder_w<<<(512 * 32 + 255) / 256, 256, 0, stream>>>(Whh1, ws + OFF_L1WH, 32, 512 * 32);
  combine_bias<<<2, 256, 0, stream>>>(bih_cell, bhh_cell, ws + OFF_GENB);
  combine_bias<<<2, 256, 0, stream>>>(bih0, bhh0, ws + OFF_L0B);
  combine_bias<<<2, 256, 0, stream>>>(bih1, bhh1, ws + OFF_L1B);

  lstm_fused<<<B / 64, 1024, 0, stream>>>(measurement, basis_r, basis_i, rho, h0, c0,
                                          Wp, bp, Whr0, Whr1, ws, out);
}